// Round 4
// baseline (81.309 us; speedup 1.0000x reference)
//
#include <hip/hip_runtime.h>

#define TPB 256
#define WQ_BYTES 589824  // 32*18*64*8*2

typedef __attribute__((ext_vector_type(8))) short short8;
typedef __attribute__((ext_vector_type(4))) float f32x4;

__device__ __forceinline__ unsigned f2bf_pk(float a, float b) {
  return ((__float_as_uint(a) + 0x8000u) >> 16) | ((__float_as_uint(b) + 0x8000u) & 0xffff0000u);
}
__device__ __forceinline__ float bflo(unsigned v) { return __uint_as_float(v << 16); }
__device__ __forceinline__ float bfhi(unsigned v) { return __uint_as_float(v & 0xffff0000u); }

// Cross-lane half-swap adds on the VALU pipe (instead of ds_bpermute/LDS).
// MUST use the builtins, not inline asm: v_permlane*_swap has a
// VALU-write -> permlane-read hazard needing compiler-inserted wait states
// (Round-3's hand asm violated it -> nondeterministic corruption).
// Same-value operands are safe: the instr defines two results, so regalloc
// duplicates into distinct physical regs.
__device__ __forceinline__ float swap16_add(float v) {
  auto r = __builtin_amdgcn_permlane16_swap(__float_as_uint(v), __float_as_uint(v), false, false);
  return __uint_as_float(r[0]) + __uint_as_float(r[1]);  // == v + v[lane^16]
}
__device__ __forceinline__ float swap32_add(float v) {
  auto r = __builtin_amdgcn_permlane32_swap(__float_as_uint(v), __float_as_uint(v), false, false);
  return __uint_as_float(r[0]) + __uint_as_float(r[1]);  // == v + v[lane^32]
}

// ---- prep: permuted bf16 A-fragment table (row permute makes each lane's
// 18x4 accumulator exactly 8 cin x 9 k for one pixel). Block 0 additionally
// scans bp for nonzeros and writes a flag (consumed by dppc9: the bench's
// predictor bias is all-zero, letting the main kernel skip all 18 C-operand
// LDS reads per oo). -------------------------------------------------------
__global__ void prep_kernel(const float* __restrict__ Wp, const float* __restrict__ bp,
                            unsigned* __restrict__ Wq, unsigned* __restrict__ flag) {
  int idx = blockIdx.x * blockDim.x + threadIdx.x;  // 147456 u32
  if (idx < 32 * 18 * 64 * 4) {
    int j2   = idx & 3;
    int lane = (idx >> 2) & 63;
    int rt   = (idx >> 8) % 18;
    int o    = (idx >> 8) / 18;
    int m16 = lane & 15, kq = lane >> 4;
    int row = o * 288 + (m16 >> 2) * 72 + rt * 4 + (m16 & 3);
    const float* src = Wp + row * 32 + kq * 8 + j2 * 2;
    Wq[idx] = f2bf_pk(src[0], src[1]);
  }
  if (blockIdx.x == 0) {
    __shared__ unsigned red[4];
    unsigned any = 0;
    for (int i = threadIdx.x; i < 2312; i += TPB) {  // 2312*4 == 9248 == PRED_OUT
      float4 v = *(const float4*)(bp + i * 4);
      any |= (v.x != 0.f) | (v.y != 0.f) | (v.z != 0.f) | (v.w != 0.f);
    }
    unsigned wv_any = (__ballot(any) != 0ull) ? 1u : 0u;
    if ((threadIdx.x & 63) == 0) red[threadIdx.x >> 6] = wv_any;
    __syncthreads();
    if (threadIdx.x == 0) flag[0] = red[0] | red[1] | red[2] | red[3];
  }
}

// ---- main: 1024 blocks = 4/CU resident (16 waves/CU). A-fragments read
// directly from global Wq (og == XCD id -> L1/L2-broadcast across the CU's
// 16 waves), sched_barrier-pinned 6-load/6-MFMA groups (Round-1 spill fix).
// LDS issue pipe cut 57 -> 11 ops/wave-oo: bias C-operand reads skipped
// when bp==0 (runtime flag), ALL butterflies moved to VALU via
// permlane16/32_swap builtins, bfrag/center/kk4-tap deduplicated to one
// read, Wb reads vectorized.
template <bool USE_WQ>
__global__ __launch_bounds__(TPB, 4) void dppc9_kernel(
    const float* __restrict__ x, const float* __restrict__ Wp,
    const float* __restrict__ bp, const unsigned* __restrict__ Wq,
    const unsigned* __restrict__ flag, float* __restrict__ out) {
  // [r 0..2][ww 0..65][c 0..31 pad40], bf16; stride 40 shorts = 80 B
  __shared__ __align__(16) unsigned short xrow2[3 * 66 * 40];   // 15840 B
  __shared__ __align__(16) float bp_s[4 * 288];                 // 4608 B
  __shared__ __align__(16) float Wb_s[4 * 32];                  // 512 B
  __shared__ float bias4[4];

  const int tid = threadIdx.x;
  const int bid = blockIdx.x;
  const int og  = bid & 7;      // couts og*4 .. og*4+3  (== XCD id)
  const int t   = bid >> 3;
  const int b   = t >> 6;
  const int h   = t & 63;

  const bool hasb = USE_WQ ? (flag[0] != 0u) : true;  // block-uniform

  const char* wq_g = (const char*)Wq + (size_t)(og * 4) * 18432;

  // prelude: side-halo zero words (disjoint from interior) + interior stage
  for (int i = tid; i < 120; i += TPB) {      // 6 (r,ww-halo) slots x 20 words
    int p = i / 20, w = i % 20;
    ((unsigned*)xrow2)[(((p >> 1) * 66 + ((p & 1) ? 65 : 0)) * 20) + w] = 0;
  }
  for (int i = tid; i < 1536; i += TPB) {     // r(3) x c4(8) x px(64)
    int px_ = i & 63, c4 = (i >> 6) & 7, r = i >> 9;
    int hh = h - 1 + r;
    unsigned w0 = 0, w1 = 0;
    if ((unsigned)hh < 64u) {
      const float* xp = x + ((b * 32 + c4 * 4) * 64 + hh) * 64 + px_;
      float f0 = xp[0], f1 = xp[4096], f2 = xp[8192], f3 = xp[12288];
      w0 = f2bf_pk(f0, f1);
      w1 = f2bf_pk(f2, f3);
    }
    uint2* dst = (uint2*)&xrow2[(r * 66 + 1 + px_) * 40 + c4 * 4];
    *dst = make_uint2(w0, w1);
  }
  if (hasb) {
    for (int i = tid; i < 1152; i += TPB) bp_s[i] = bp[og * 1152 + i];
    if (tid < 4) bias4[tid] = bp[9216 + og * 4 + tid];
  }
  if (tid < 128) Wb_s[tid] = Wp[(9216 + og * 4 + (tid >> 5)) * 32 + (tid & 31)];
  __syncthreads();   // the ONLY barrier

  const int lane = tid & 63;
  const int wv   = tid >> 6;
  const int m16  = lane & 15, kq = lane >> 4;
  const int px   = wv * 16 + m16;

#pragma unroll 1
  for (int oo = 0; oo < 4; ++oo) {
    const int o = og * 4 + oo;

    // one b128 read serves: MFMA B-fragment, pass-B kk=4 tap, epilogue
    // center tap (all the same 16 B of xrow2).
    const uint4 cent = *(const uint4*)&xrow2[(66 + 1 + px) * 40 + kq * 8];
    const short8 bfrag = *(const short8*)&cent;

    // phase 1: 18 MFMAs; strict 6-load / 6-MFMA groups pinned by
    // sched_barrier(0) (keeps at most 24 A-VGPRs in flight; Round-1's
    // unconstrained hoist of all 18 loads spilled).
    f32x4 acc[18];
    if (USE_WQ) {
      const char* ap = wq_g + ((oo * 1152 + lane) << 4);
      if (hasb) {
#pragma unroll
        for (int g = 0; g < 3; ++g) {
          short8 a6[6];
#pragma unroll
          for (int j = 0; j < 6; ++j)
            a6[j] = *(const short8*)(ap + (((g * 6 + j) << 10)));
          __builtin_amdgcn_sched_barrier(0);
#pragma unroll
          for (int j = 0; j < 6; ++j) {
            const int rt = g * 6 + j;
            const f32x4 bb = *(const f32x4*)&bp_s[oo * 288 + kq * 72 + rt * 4];
            acc[rt] = __builtin_amdgcn_mfma_f32_16x16x32_bf16(a6[j], bfrag, bb, 0, 0, 0);
          }
          __builtin_amdgcn_sched_barrier(0);
        }
      } else {
        const f32x4 z = {0.f, 0.f, 0.f, 0.f};
#pragma unroll
        for (int g = 0; g < 3; ++g) {
          short8 a6[6];
#pragma unroll
          for (int j = 0; j < 6; ++j)
            a6[j] = *(const short8*)(ap + (((g * 6 + j) << 10)));
          __builtin_amdgcn_sched_barrier(0);
#pragma unroll
          for (int j = 0; j < 6; ++j)
            acc[g * 6 + j] = __builtin_amdgcn_mfma_f32_16x16x32_bf16(a6[j], bfrag, z, 0, 0, 0);
          __builtin_amdgcn_sched_barrier(0);
        }
      }
    } else {
      const float* ab = Wp + (o * 288 + (m16 >> 2) * 72 + (m16 & 3)) * 32 + kq * 8;
#pragma unroll
      for (int rt = 0; rt < 18; ++rt) {
        const float* ap = ab + rt * 4 * 32;
        float4 a0 = *(const float4*)ap;
        float4 a1 = *(const float4*)(ap + 4);
        union { short8 v; unsigned u[4]; } af;
        af.u[0] = f2bf_pk(a0.x, a0.y);
        af.u[1] = f2bf_pk(a0.z, a0.w);
        af.u[2] = f2bf_pk(a1.x, a1.y);
        af.u[3] = f2bf_pk(a1.z, a1.w);
        const f32x4 bb = *(const f32x4*)&bp_s[oo * 288 + kq * 72 + rt * 4];
        acc[rt] = __builtin_amdgcn_mfma_f32_16x16x32_bf16(af.v, bfrag, bb, 0, 0, 0);
      }
    }

    // cin-norm denominators: local partial + reduce across kq (bits 4,5)
    // entirely on the VALU via permlane swaps (same FP summation order as
    // the old shfl_xor16 -> shfl_xor32 chain).
    float rinv[9];
#pragma unroll
    for (int kk = 0; kk < 9; ++kk) rinv[kk] = 0.f;
#pragma unroll
    for (int c8 = 0; c8 < 8; ++c8)
#pragma unroll
      for (int kk = 0; kk < 9; ++kk) {
        const int idx = c8 * 9 + kk;
        const float v = acc[idx >> 2][idx & 3];
        rinv[kk] += v * v;
      }
#pragma unroll
    for (int kk = 0; kk < 9; ++kk) {
      float s = rinv[kk];
      s = swap16_add(s);
      s = swap32_add(s);
      rinv[kk] = rsqrtf(fmaxf(s, 1e-24f));  // == 1/max(sqrt(s),1e-12)
    }

    // pass B: per tap k one b128 patch read (kk=4 reuses cent), s2/dot
    // accumulated per c8; k-norm applied in the epilogue.
    float s2[8], dot[8];
#pragma unroll
    for (int c8 = 0; c8 < 8; ++c8) { s2[c8] = 0.f; dot[c8] = 0.f; }
#pragma unroll
    for (int kk = 0; kk < 9; ++kk) {
      const int kh = kk / 3, kw = kk - kh * 3;
      const uint4 tp = (kk == 4) ? cent
                                 : *(const uint4*)&xrow2[(kh * 66 + kw + px) * 40 + kq * 8];
      const float rv = rinv[kk];
#pragma unroll
      for (int c8 = 0; c8 < 8; ++c8) {
        const int idx = c8 * 9 + kk;
        const float tv = acc[idx >> 2][idx & 3] * rv;
        s2[c8] += tv * tv;
        const unsigned wd = ((const unsigned*)&tp)[c8 >> 1];
        const float pv = (c8 & 1) ? bfhi(wd) : bflo(wd);
        dot[c8] += tv * pv;
      }
    }

    // epilogue: combine per-c8, add dyn-bias partials, butterfly, store.
    const f32x4 wb0 = *(const f32x4*)&Wb_s[oo * 32 + kq * 8];
    const f32x4 wb1 = *(const f32x4*)&Wb_s[oo * 32 + kq * 8 + 4];
    float oacc = 0.f;
#pragma unroll
    for (int c8 = 0; c8 < 8; ++c8) {
      oacc += rsqrtf(fmaxf(s2[c8], 1e-24f)) * dot[c8];
      const unsigned wd = ((const unsigned*)&cent)[c8 >> 1];
      const float xc = (c8 & 1) ? bfhi(wd) : bflo(wd);
      const float wbv = (c8 < 4) ? wb0[c8] : wb1[c8 - 4];
      oacc += wbv * xc;
    }
    oacc = swap16_add(oacc);
    oacc = swap32_add(oacc);
    if (kq == 0) {
      float b4 = 0.f;
      if (hasb) b4 = bias4[oo];
      out[((b * 32 + o) * 64 + h) * 64 + px] = oacc + b4;
    }
  }
}

extern "C" void kernel_launch(void* const* d_in, const int* in_sizes, int n_in,
                              void* d_out, int out_size, void* d_ws, size_t ws_size,
                              hipStream_t stream) {
  const float* x  = (const float*)d_in[0];
  const float* Wp = (const float*)d_in[1];
  const float* bp = (const float*)d_in[2];
  float* out = (float*)d_out;
  if (ws_size >= WQ_BYTES + 4) {
    unsigned* wq   = (unsigned*)d_ws;
    unsigned* flag = (unsigned*)((char*)d_ws + WQ_BYTES);
    prep_kernel<<<576, 256, 0, stream>>>(Wp, bp, wq, flag);
    dppc9_kernel<true><<<1024, TPB, 0, stream>>>(x, Wp, bp, wq, flag, out);
  } else {
    dppc9_kernel<false><<<1024, TPB, 0, stream>>>(x, Wp, bp, nullptr, nullptr, out);
  }
}

// Round 5
// 80.010 us; speedup vs baseline: 1.0162x; 1.0162x over previous
//
#include <hip/hip_runtime.h>

#define TPB 256
#define WQ_BYTES 589824  // 32*18*64*8*2

typedef __attribute__((ext_vector_type(8))) short short8;
typedef __attribute__((ext_vector_type(4))) float f32x4;

__device__ __forceinline__ unsigned f2bf_pk(float a, float b) {
  return ((__float_as_uint(a) + 0x8000u) >> 16) | ((__float_as_uint(b) + 0x8000u) & 0xffff0000u);
}
__device__ __forceinline__ float bflo(unsigned v) { return __uint_as_float(v << 16); }
__device__ __forceinline__ float bfhi(unsigned v) { return __uint_as_float(v & 0xffff0000u); }

// Cross-lane half-swap adds on the VALU pipe. MUST use the builtins, not
// inline asm: v_permlane*_swap has a VALU-write -> permlane-read hazard
// needing compiler-inserted wait states (Round-3's hand asm violated it ->
// nondeterministic corruption; Round-4's builtins verified correct).
__device__ __forceinline__ float swap16_add(float v) {
  auto r = __builtin_amdgcn_permlane16_swap(__float_as_uint(v), __float_as_uint(v), false, false);
  return __uint_as_float(r[0]) + __uint_as_float(r[1]);  // == v + v[lane^16]
}
__device__ __forceinline__ float swap32_add(float v) {
  auto r = __builtin_amdgcn_permlane32_swap(__float_as_uint(v), __float_as_uint(v), false, false);
  return __uint_as_float(r[0]) + __uint_as_float(r[1]);  // == v + v[lane^32]
}

// ---- prep: permuted bf16 A-fragment table (row permute makes each lane's
// 18x4 accumulator exactly 8 cin x 9 k for one pixel). Pure table build —
// R4's bp-scan regressed prep's critical path and is removed. -------------
__global__ void prep_kernel(const float* __restrict__ Wp, unsigned* __restrict__ Wq) {
  int idx = blockIdx.x * blockDim.x + threadIdx.x;  // 147456 u32
  if (idx >= 32 * 18 * 64 * 4) return;
  int j2   = idx & 3;
  int lane = (idx >> 2) & 63;
  int rt   = (idx >> 8) % 18;
  int o    = (idx >> 8) / 18;
  int m16 = lane & 15, kq = lane >> 4;
  int row = o * 288 + (m16 >> 2) * 72 + rt * 4 + (m16 & 3);
  const float* src = Wp + row * 32 + kq * 8 + j2 * 2;
  Wq[idx] = f2bf_pk(src[0], src[1]);
}

// ---- main: 1024 blocks = 4/CU resident (16 waves/CU). A-fragments read
// directly from global Wq (og == XCD id -> L1/L2-broadcast across the CU's
// 16 waves). Phase 1 is a depth-2 software pipeline at 6-fragment
// granularity: L0 | L1 M0 | L2 M1 | M2 — group g+1's loads fly under group
// g's MFMAs, so only the first group's L2 latency is exposed (R2's fully
// serial pinning exposed all three). sched_barrier(0) pins keep the live
// A-set at <=48 VGPRs (R1's unconstrained hoist of all 18 spilled).
// Permlane swaps / cent-dedup / vectorized Wb kept from R4 (verified).
template <bool USE_WQ>
__global__ __launch_bounds__(TPB, 4) void dppc9_kernel(
    const float* __restrict__ x, const float* __restrict__ Wp,
    const float* __restrict__ bp, const unsigned* __restrict__ Wq,
    float* __restrict__ out) {
  // [r 0..2][ww 0..65][c 0..31 pad40], bf16; stride 40 shorts = 80 B
  __shared__ __align__(16) unsigned short xrow2[3 * 66 * 40];   // 15840 B
  __shared__ __align__(16) float bp_s[4 * 288];                 // 4608 B
  __shared__ __align__(16) float Wb_s[4 * 32];                  // 512 B
  __shared__ float bias4[4];

  const int tid = threadIdx.x;
  const int bid = blockIdx.x;
  const int og  = bid & 7;      // couts og*4 .. og*4+3  (== XCD id)
  const int t   = bid >> 3;
  const int b   = t >> 6;
  const int h   = t & 63;

  const char* wq_g = (const char*)Wq + (size_t)(og * 4) * 18432;

  // prelude: side-halo zero words (disjoint from interior) + interior stage
  for (int i = tid; i < 120; i += TPB) {      // 6 (r,ww-halo) slots x 20 words
    int p = i / 20, w = i % 20;
    ((unsigned*)xrow2)[(((p >> 1) * 66 + ((p & 1) ? 65 : 0)) * 20) + w] = 0;
  }
  for (int i = tid; i < 1536; i += TPB) {     // r(3) x c4(8) x px(64)
    int px_ = i & 63, c4 = (i >> 6) & 7, r = i >> 9;
    int hh = h - 1 + r;
    unsigned w0 = 0, w1 = 0;
    if ((unsigned)hh < 64u) {
      const float* xp = x + ((b * 32 + c4 * 4) * 64 + hh) * 64 + px_;
      float f0 = xp[0], f1 = xp[4096], f2 = xp[8192], f3 = xp[12288];
      w0 = f2bf_pk(f0, f1);
      w1 = f2bf_pk(f2, f3);
    }
    uint2* dst = (uint2*)&xrow2[(r * 66 + 1 + px_) * 40 + c4 * 4];
    *dst = make_uint2(w0, w1);
  }
  for (int i = tid; i < 1152; i += TPB) bp_s[i] = bp[og * 1152 + i];
  if (tid < 128) Wb_s[tid] = Wp[(9216 + og * 4 + (tid >> 5)) * 32 + (tid & 31)];
  if (tid < 4) bias4[tid] = bp[9216 + og * 4 + tid];
  __syncthreads();   // the ONLY barrier

  const int lane = tid & 63;
  const int wv   = tid >> 6;
  const int m16  = lane & 15, kq = lane >> 4;
  const int px   = wv * 16 + m16;

#pragma unroll 1
  for (int oo = 0; oo < 4; ++oo) {
    const int o = og * 4 + oo;

    // one b128 read serves: MFMA B-fragment, pass-B kk=4 tap, epilogue
    // center tap (all the same 16 B of xrow2).
    const uint4 cent = *(const uint4*)&xrow2[(66 + 1 + px) * 40 + kq * 8];
    const short8 bfrag = *(const short8*)&cent;

    // phase 1: 18 MFMAs, predictor bias folded into C-operand.
    // lane holds pred fp32 for idx=c8*9+k (cin=kq*8+c8) at px: acc[idx>>2][idx&3]
    f32x4 acc[18];
    if (USE_WQ) {
      const char* ap = wq_g + ((oo * 1152 + lane) << 4);
      const float* bbp = &bp_s[oo * 288 + kq * 72];
      short8 aA[6], aB[6];
      // L0
#pragma unroll
      for (int j = 0; j < 6; ++j) aA[j] = *(const short8*)(ap + (j << 10));
      __builtin_amdgcn_sched_barrier(0);
      // L1 (in flight under M0)
#pragma unroll
      for (int j = 0; j < 6; ++j) aB[j] = *(const short8*)(ap + ((6 + j) << 10));
      __builtin_amdgcn_sched_barrier(0);
      // M0
#pragma unroll
      for (int j = 0; j < 6; ++j) {
        const f32x4 bb = *(const f32x4*)(bbp + j * 4);
        acc[j] = __builtin_amdgcn_mfma_f32_16x16x32_bf16(aA[j], bfrag, bb, 0, 0, 0);
      }
      __builtin_amdgcn_sched_barrier(0);
      // L2 (in flight under M1), reuses aA
#pragma unroll
      for (int j = 0; j < 6; ++j) aA[j] = *(const short8*)(ap + ((12 + j) << 10));
      __builtin_amdgcn_sched_barrier(0);
      // M1
#pragma unroll
      for (int j = 0; j < 6; ++j) {
        const f32x4 bb = *(const f32x4*)(bbp + (6 + j) * 4);
        acc[6 + j] = __builtin_amdgcn_mfma_f32_16x16x32_bf16(aB[j], bfrag, bb, 0, 0, 0);
      }
      __builtin_amdgcn_sched_barrier(0);
      // M2
#pragma unroll
      for (int j = 0; j < 6; ++j) {
        const f32x4 bb = *(const f32x4*)(bbp + (12 + j) * 4);
        acc[12 + j] = __builtin_amdgcn_mfma_f32_16x16x32_bf16(aA[j], bfrag, bb, 0, 0, 0);
      }
      __builtin_amdgcn_sched_barrier(0);
    } else {
      const float* ab = Wp + (o * 288 + (m16 >> 2) * 72 + (m16 & 3)) * 32 + kq * 8;
#pragma unroll
      for (int rt = 0; rt < 18; ++rt) {
        const float* ap = ab + rt * 4 * 32;
        float4 a0 = *(const float4*)ap;
        float4 a1 = *(const float4*)(ap + 4);
        union { short8 v; unsigned u[4]; } af;
        af.u[0] = f2bf_pk(a0.x, a0.y);
        af.u[1] = f2bf_pk(a0.z, a0.w);
        af.u[2] = f2bf_pk(a1.x, a1.y);
        af.u[3] = f2bf_pk(a1.z, a1.w);
        const f32x4 bb = *(const f32x4*)&bp_s[oo * 288 + kq * 72 + rt * 4];
        acc[rt] = __builtin_amdgcn_mfma_f32_16x16x32_bf16(af.v, bfrag, bb, 0, 0, 0);
      }
    }

    // cin-norm denominators: local partial + reduce across kq (bits 4,5)
    // on the VALU via permlane swaps (same FP order as the shfl chain).
    float rinv[9];
#pragma unroll
    for (int kk = 0; kk < 9; ++kk) rinv[kk] = 0.f;
#pragma unroll
    for (int c8 = 0; c8 < 8; ++c8)
#pragma unroll
      for (int kk = 0; kk < 9; ++kk) {
        const int idx = c8 * 9 + kk;
        const float v = acc[idx >> 2][idx & 3];
        rinv[kk] += v * v;
      }
#pragma unroll
    for (int kk = 0; kk < 9; ++kk) {
      float s = rinv[kk];
      s = swap16_add(s);
      s = swap32_add(s);
      rinv[kk] = rsqrtf(fmaxf(s, 1e-24f));  // == 1/max(sqrt(s),1e-12)
    }

    // pass B: per tap k one b128 patch read (kk=4 reuses cent), s2/dot
    // accumulated per c8; k-norm applied in the epilogue.
    float s2[8], dot[8];
#pragma unroll
    for (int c8 = 0; c8 < 8; ++c8) { s2[c8] = 0.f; dot[c8] = 0.f; }
#pragma unroll
    for (int kk = 0; kk < 9; ++kk) {
      const int kh = kk / 3, kw = kk - kh * 3;
      const uint4 tp = (kk == 4) ? cent
                                 : *(const uint4*)&xrow2[(kh * 66 + kw + px) * 40 + kq * 8];
      const float rv = rinv[kk];
#pragma unroll
      for (int c8 = 0; c8 < 8; ++c8) {
        const int idx = c8 * 9 + kk;
        const float tv = acc[idx >> 2][idx & 3] * rv;
        s2[c8] += tv * tv;
        const unsigned wd = ((const unsigned*)&tp)[c8 >> 1];
        const float pv = (c8 & 1) ? bfhi(wd) : bflo(wd);
        dot[c8] += tv * pv;
      }
    }

    // epilogue: combine per-c8, add dyn-bias partials, butterfly, store.
    const f32x4 wb0 = *(const f32x4*)&Wb_s[oo * 32 + kq * 8];
    const f32x4 wb1 = *(const f32x4*)&Wb_s[oo * 32 + kq * 8 + 4];
    float oacc = 0.f;
#pragma unroll
    for (int c8 = 0; c8 < 8; ++c8) {
      oacc += rsqrtf(fmaxf(s2[c8], 1e-24f)) * dot[c8];
      const unsigned wd = ((const unsigned*)&cent)[c8 >> 1];
      const float xc = (c8 & 1) ? bfhi(wd) : bflo(wd);
      const float wbv = (c8 < 4) ? wb0[c8] : wb1[c8 - 4];
      oacc += wbv * xc;
    }
    oacc = swap16_add(oacc);
    oacc = swap32_add(oacc);
    if (kq == 0)
      out[((b * 32 + o) * 64 + h) * 64 + px] = oacc + bias4[oo];
  }
}

extern "C" void kernel_launch(void* const* d_in, const int* in_sizes, int n_in,
                              void* d_out, int out_size, void* d_ws, size_t ws_size,
                              hipStream_t stream) {
  const float* x  = (const float*)d_in[0];
  const float* Wp = (const float*)d_in[1];
  const float* bp = (const float*)d_in[2];
  float* out = (float*)d_out;
  if (ws_size >= WQ_BYTES) {
    prep_kernel<<<576, 256, 0, stream>>>(Wp, (unsigned*)d_ws);
    dppc9_kernel<true><<<1024, TPB, 0, stream>>>(x, Wp, bp, (const unsigned*)d_ws, out);
  } else {
    dppc9_kernel<false><<<1024, TPB, 0, stream>>>(x, Wp, bp, nullptr, out);
  }
}